// Round 1
// baseline (1382.321 us; speedup 1.0000x reference)
//
#include <hip/hip_runtime.h>
#include <hip/hip_bf16.h>
#include <cstdint>

#define T_TOK 8192
#define HD 1024
#define FD 4096
#define NE 8
#define CAP 17408  /* 16384 assignments + 8*128 alignment pad */

typedef __attribute__((ext_vector_type(8))) short bf16x8;
typedef __attribute__((ext_vector_type(4))) float f32x4;

// fp32 -> bf16 round-to-nearest-even (inputs finite)
__device__ __forceinline__ unsigned short f2bf(float f) {
  union { float f; unsigned int u; } a; a.f = f;
  unsigned int r = a.u + 0x7fffu + ((a.u >> 16) & 1u);
  return (unsigned short)(r >> 16);
}

// XOR swizzle within a 128B LDS row: spreads 16B column-slices across banks
#define SWZ(row, kb) ((kb) ^ (((row) & 7) << 4))

// ---------------------------------------------------------------- gating
__global__ __launch_bounds__(256) void k_gate(
    const float* __restrict__ x, const float* __restrict__ gw,
    float* __restrict__ logits, int* __restrict__ pe1, int* __restrict__ pe2,
    float* __restrict__ pw1, float* __restrict__ pw2) {
  int wid = threadIdx.x >> 6, lane = threadIdx.x & 63;
  int t = blockIdx.x * 4 + wid;
  const float* xr = x + (size_t)t * HD;
  float acc[NE];
#pragma unroll
  for (int e = 0; e < NE; ++e) acc[e] = 0.f;
  for (int j = 0; j < HD / 64; ++j) {
    float xv = xr[j * 64 + lane];
#pragma unroll
    for (int e = 0; e < NE; ++e) acc[e] += xv * gw[e * HD + j * 64 + lane];
  }
#pragma unroll
  for (int e = 0; e < NE; ++e) {
    float v = acc[e];
#pragma unroll
    for (int m = 32; m; m >>= 1) v += __shfl_xor(v, m, 64);
    acc[e] = v;
  }
  // every lane now holds all 8 logits
  if (lane < NE) {
    float v = acc[0];
#pragma unroll
    for (int e = 1; e < NE; ++e) if (lane == e) v = acc[e];
    logits[(size_t)t * NE + lane] = v;
  }
  // top-2, ties -> lowest index (matches lax.top_k)
  int i1 = 0; float m1 = acc[0];
#pragma unroll
  for (int e = 1; e < NE; ++e) if (acc[e] > m1) { m1 = acc[e]; i1 = e; }
  int i2 = -1; float m2 = -3.4e38f;
#pragma unroll
  for (int e = 0; e < NE; ++e) if (e != i1 && acc[e] > m2) { m2 = acc[e]; i2 = e; }
  float z  = expf(m2 - m1);          // in (0,1]
  float wa = 1.f / (1.f + z);
  float wb = z  / (1.f + z);
  if (lane == 0) { pe1[t] = i1; pe2[t] = i2; pw1[t] = wa; pw2[t] = wb; }
}

// ---------------------------------------------------------------- counts + 128-aligned offsets
__global__ void k_count(const int* __restrict__ pe1, const int* __restrict__ pe2,
                        int* __restrict__ cnt, int* __restrict__ off) {
  __shared__ int sc[NE];
  int wid = threadIdx.x >> 6, lane = threadIdx.x & 63;  // 512 threads = 8 waves
  int c = 0;
  for (int t = lane; t < T_TOK; t += 64) c += (pe1[t] == wid) + (pe2[t] == wid);
#pragma unroll
  for (int m = 32; m; m >>= 1) c += __shfl_xor(c, m, 64);
  if (lane == 0) sc[wid] = c;
  __syncthreads();
  if (threadIdx.x == 0) {
    int o = 0;
    for (int e = 0; e < NE; ++e) { cnt[e] = sc[e]; off[e] = o; o += (sc[e] + 127) & ~127; }
  }
}

// ---------------------------------------------------------------- stable per-expert token lists
__global__ void k_build(const int* __restrict__ pe1, const int* __restrict__ pe2,
                        const float* __restrict__ pw1, const float* __restrict__ pw2,
                        const int* __restrict__ cnt, const int* __restrict__ off,
                        int* __restrict__ tok_c, float* __restrict__ wgt_c) {
  int e = blockIdx.x;
  int base = off[e], n = cnt[e];
  __shared__ int sc[256];
  int written = 0;
  for (int c0 = 0; c0 < T_TOK; c0 += 1024) {
    int tb = c0 + threadIdx.x * 4;
    int f[4]; float w[4]; int fc = 0;
#pragma unroll
    for (int q = 0; q < 4; ++q) {
      int t = tb + q;
      int a = (pe1[t] == e), b = (pe2[t] == e);
      f[q] = a | b;
      w[q] = a ? pw1[t] : pw2[t];
      fc += f[q];
    }
    sc[threadIdx.x] = fc;
    __syncthreads();
    for (int s = 1; s < 256; s <<= 1) {
      int v = sc[threadIdx.x];
      int u = (threadIdx.x >= s) ? sc[threadIdx.x - s] : 0;
      __syncthreads();
      sc[threadIdx.x] = v + u;
      __syncthreads();
    }
    int excl = sc[threadIdx.x] - fc;
    int tot  = sc[255];
    int pos  = base + written + excl;
#pragma unroll
    for (int q = 0; q < 4; ++q)
      if (f[q]) { tok_c[pos] = tb + q; wgt_c[pos] = w[q]; ++pos; }
    written += tot;
    __syncthreads();
  }
  int aligned = (n + 127) & ~127;
  for (int i = n + threadIdx.x; i < aligned; i += 256) { tok_c[base + i] = 0; wgt_c[base + i] = 0.f; }
}

// ---------------------------------------------------------------- gather x rows -> bf16, expert-sorted
__global__ __launch_bounds__(256) void k_gather(
    const float* __restrict__ x, const int* __restrict__ tok_c,
    const int* __restrict__ cnt, const int* __restrict__ off,
    unsigned short* __restrict__ xg) {
  int e = blockIdx.y;
  int n = cnt[e];
  int row = blockIdx.x * 8 + (threadIdx.x >> 5);
  if (row >= n) return;
  int base = off[e];
  int tok = tok_c[base + row];
  int c = threadIdx.x & 31;
  const float4* src = (const float4*)(x + (size_t)tok * HD);
  unsigned short* dst = xg + (size_t)(base + row) * HD;
#pragma unroll
  for (int q = 0; q < 8; ++q) {
    float4 v = src[q * 32 + c];
    ushort4 o;
    o.x = f2bf(v.x); o.y = f2bf(v.y); o.z = f2bf(v.z); o.w = f2bf(v.w);
    *(ushort4*)(dst + (size_t)(q * 32 + c) * 4) = o;
  }
}

// ---------------------------------------------------------------- GEMM1: g=x@w1^T, u=x@w3^T, h=silu(g)*u
// BM=128, BN=64 (per matrix), BK=64, 4 waves (2x2), 16x16x32 bf16 MFMA
__global__ __launch_bounds__(256) void k_gemm1(
    const unsigned short* __restrict__ xg,
    const float* __restrict__ w1, const float* __restrict__ w3,
    unsigned short* __restrict__ h,
    const int* __restrict__ cnt, const int* __restrict__ off) {
  int e = blockIdx.z;
  int n_e = cnt[e];
  int mt0 = blockIdx.y * 128;
  if (mt0 >= n_e) return;
  int base = off[e];
  int n0 = blockIdx.x * 64;
  __shared__ unsigned short sA[128 * 64];
  __shared__ unsigned short sB1[64 * 64];
  __shared__ unsigned short sB2[64 * 64];
  int tid = threadIdx.x;
  int wid = tid >> 6, lane = tid & 63;
  int wr = wid >> 1, wc = wid & 1;
  f32x4 accg[4][2], accu[4][2];
#pragma unroll
  for (int i = 0; i < 4; ++i)
#pragma unroll
    for (int j = 0; j < 2; ++j) {
      accg[i][j] = f32x4{0.f, 0.f, 0.f, 0.f};
      accu[i][j] = f32x4{0.f, 0.f, 0.f, 0.f};
    }

  const unsigned short* Ag = xg + (size_t)(base + mt0) * HD;
  const float* B1g = w1 + (size_t)e * FD * HD + (size_t)n0 * HD;
  const float* B3g = w3 + (size_t)e * FD * HD + (size_t)n0 * HD;

  int arow = tid >> 1, acol = (tid & 1) * 32;  // 32 bf16 per thread (A)
  int brow = tid >> 2, bcol = (tid & 3) * 16;  // 16 f32 per thread per matrix (B)

  for (int k0 = 0; k0 < HD; k0 += 64) {
    __syncthreads();
    {  // stage A (already bf16)
      const int4* src = (const int4*)(Ag + (size_t)arow * HD + k0 + acol);
      char* drow = (char*)sA + arow * 128;
#pragma unroll
      for (int q = 0; q < 4; ++q)
        *(int4*)(drow + SWZ(arow, acol * 2 + q * 16)) = src[q];
    }
    {  // stage B1/B2 with fp32->bf16 cvt
      const float4* s1 = (const float4*)(B1g + (size_t)brow * HD + k0 + bcol);
      const float4* s3 = (const float4*)(B3g + (size_t)brow * HD + k0 + bcol);
      char* d1 = (char*)sB1 + brow * 128;
      char* d3 = (char*)sB2 + brow * 128;
      union { unsigned short us[8]; int4 v; } p;
#pragma unroll
      for (int hh = 0; hh < 2; ++hh) {
        float4 a = s1[hh * 2 + 0], b = s1[hh * 2 + 1];
        p.us[0] = f2bf(a.x); p.us[1] = f2bf(a.y); p.us[2] = f2bf(a.z); p.us[3] = f2bf(a.w);
        p.us[4] = f2bf(b.x); p.us[5] = f2bf(b.y); p.us[6] = f2bf(b.z); p.us[7] = f2bf(b.w);
        *(int4*)(d1 + SWZ(brow, bcol * 2 + hh * 16)) = p.v;
      }
#pragma unroll
      for (int hh = 0; hh < 2; ++hh) {
        float4 a = s3[hh * 2 + 0], b = s3[hh * 2 + 1];
        p.us[0] = f2bf(a.x); p.us[1] = f2bf(a.y); p.us[2] = f2bf(a.z); p.us[3] = f2bf(a.w);
        p.us[4] = f2bf(b.x); p.us[5] = f2bf(b.y); p.us[6] = f2bf(b.z); p.us[7] = f2bf(b.w);
        *(int4*)(d3 + SWZ(brow, bcol * 2 + hh * 16)) = p.v;
      }
    }
    __syncthreads();
#pragma unroll
    for (int kk = 0; kk < 2; ++kk) {
      int kb = kk * 64 + (lane >> 4) * 16;
      bf16x8 af[4], b1f[2], b2f[2];
#pragma unroll
      for (int mt = 0; mt < 4; ++mt) {
        int r = wr * 64 + mt * 16 + (lane & 15);
        af[mt] = *(const bf16x8*)((const char*)sA + r * 128 + SWZ(r, kb));
      }
#pragma unroll
      for (int nt = 0; nt < 2; ++nt) {
        int r = wc * 32 + nt * 16 + (lane & 15);
        b1f[nt] = *(const bf16x8*)((const char*)sB1 + r * 128 + SWZ(r, kb));
        b2f[nt] = *(const bf16x8*)((const char*)sB2 + r * 128 + SWZ(r, kb));
      }
#pragma unroll
      for (int mt = 0; mt < 4; ++mt)
#pragma unroll
        for (int nt = 0; nt < 2; ++nt) {
          accg[mt][nt] = __builtin_amdgcn_mfma_f32_16x16x32_bf16(af[mt], b1f[nt], accg[mt][nt], 0, 0, 0);
          accu[mt][nt] = __builtin_amdgcn_mfma_f32_16x16x32_bf16(af[mt], b2f[nt], accu[mt][nt], 0, 0, 0);
        }
    }
  }
  // epilogue: h = silu(g)*u -> bf16 (C/D layout: col=lane&15, row=(lane>>4)*4+r)
#pragma unroll
  for (int mt = 0; mt < 4; ++mt) {
    int rbase = wr * 64 + mt * 16 + ((lane >> 4) << 2);
#pragma unroll
    for (int r = 0; r < 4; ++r) {
      int lrow = rbase + r;
      if (mt0 + lrow < n_e) {
        size_t hrow = (size_t)(base + mt0 + lrow) * FD;
#pragma unroll
        for (int nt = 0; nt < 2; ++nt) {
          int col = n0 + wc * 32 + nt * 16 + (lane & 15);
          float g = accg[mt][nt][r], u = accu[mt][nt][r];
          float s = g / (1.f + expf(-g));
          h[hrow + col] = f2bf(s * u);
        }
      }
    }
  }
}

// ---------------------------------------------------------------- GEMM2: y=h@w2^T, out[tok]+=w*y
// BM=128, BN=128, BK=64, 4 waves (2x2)
__global__ __launch_bounds__(256) void k_gemm2(
    const unsigned short* __restrict__ h, const float* __restrict__ w2,
    float* __restrict__ out,
    const int* __restrict__ cnt, const int* __restrict__ off,
    const int* __restrict__ tok_c, const float* __restrict__ wgt_c) {
  int e = blockIdx.z;
  int n_e = cnt[e];
  int mt0 = blockIdx.y * 128;
  if (mt0 >= n_e) return;
  int base = off[e];
  int n0 = blockIdx.x * 128;
  __shared__ unsigned short sA[128 * 64];
  __shared__ unsigned short sB[128 * 64];
  int tid = threadIdx.x, wid = tid >> 6, lane = tid & 63;
  int wr = wid >> 1, wc = wid & 1;
  f32x4 acc[4][4];
#pragma unroll
  for (int i = 0; i < 4; ++i)
#pragma unroll
    for (int j = 0; j < 4; ++j) acc[i][j] = f32x4{0.f, 0.f, 0.f, 0.f};

  const unsigned short* Ag = h + (size_t)(base + mt0) * FD;
  const float* Bg = w2 + (size_t)e * HD * FD + (size_t)n0 * FD;

  int arow = tid >> 1, acol = (tid & 1) * 32;  // 32 bf16 per thread
  int brow = tid >> 1, bcol = (tid & 1) * 32;  // 32 f32 per thread

  for (int k0 = 0; k0 < FD; k0 += 64) {
    __syncthreads();
    {
      const int4* src = (const int4*)(Ag + (size_t)arow * FD + k0 + acol);
      char* drow = (char*)sA + arow * 128;
#pragma unroll
      for (int q = 0; q < 4; ++q)
        *(int4*)(drow + SWZ(arow, acol * 2 + q * 16)) = src[q];
    }
    {
      const float4* src = (const float4*)(Bg + (size_t)brow * FD + k0 + bcol);
      char* drow = (char*)sB + brow * 128;
      union { unsigned short us[8]; int4 v; } p;
#pragma unroll
      for (int q = 0; q < 4; ++q) {
        float4 a = src[q * 2 + 0], b = src[q * 2 + 1];
        p.us[0] = f2bf(a.x); p.us[1] = f2bf(a.y); p.us[2] = f2bf(a.z); p.us[3] = f2bf(a.w);
        p.us[4] = f2bf(b.x); p.us[5] = f2bf(b.y); p.us[6] = f2bf(b.z); p.us[7] = f2bf(b.w);
        *(int4*)(drow + SWZ(brow, bcol * 2 + q * 16)) = p.v;
      }
    }
    __syncthreads();
#pragma unroll
    for (int kk = 0; kk < 2; ++kk) {
      int kb = kk * 64 + (lane >> 4) * 16;
      bf16x8 af[4], bf[4];
#pragma unroll
      for (int mt = 0; mt < 4; ++mt) {
        int r = wr * 64 + mt * 16 + (lane & 15);
        af[mt] = *(const bf16x8*)((const char*)sA + r * 128 + SWZ(r, kb));
      }
#pragma unroll
      for (int nt = 0; nt < 4; ++nt) {
        int r = wc * 64 + nt * 16 + (lane & 15);
        bf[nt] = *(const bf16x8*)((const char*)sB + r * 128 + SWZ(r, kb));
      }
#pragma unroll
      for (int mt = 0; mt < 4; ++mt)
#pragma unroll
        for (int nt = 0; nt < 4; ++nt)
          acc[mt][nt] = __builtin_amdgcn_mfma_f32_16x16x32_bf16(af[mt], bf[nt], acc[mt][nt], 0, 0, 0);
    }
  }
  // epilogue: weighted scatter-add (each token has exactly 2 experts)
#pragma unroll
  for (int mt = 0; mt < 4; ++mt) {
    int rbase = wr * 64 + mt * 16 + ((lane >> 4) << 2);
#pragma unroll
    for (int r = 0; r < 4; ++r) {
      int grow = mt0 + rbase + r;
      if (grow < n_e) {
        int tok = tok_c[base + grow];
        float wgt = wgt_c[base + grow];
        float* orow = out + (size_t)tok * HD;
#pragma unroll
        for (int nt = 0; nt < 4; ++nt) {
          int col = n0 + wc * 64 + nt * 16 + (lane & 15);
          atomicAdd(orow + col, wgt * acc[mt][nt][r]);
        }
      }
    }
  }
}

// ----------------------------------------------------------------
extern "C" void kernel_launch(void* const* d_in, const int* in_sizes, int n_in,
                              void* d_out, int out_size, void* d_ws, size_t ws_size,
                              hipStream_t stream) {
  const float* x  = (const float*)d_in[0];
  const float* gw = (const float*)d_in[1];
  const float* w1 = (const float*)d_in[2];
  const float* w2 = (const float*)d_in[3];
  const float* w3 = (const float*)d_in[4];
  float* out = (float*)d_out;
  float* logits = out + (size_t)T_TOK * HD;

  char* wsp = (char*)d_ws;
  size_t cur = 0;
  auto alloc = [&](size_t bytes) {
    char* p = wsp + cur;
    cur += (bytes + 255) & ~(size_t)255;
    return p;
  };
  int*   pe1   = (int*)alloc((size_t)T_TOK * 4);
  int*   pe2   = (int*)alloc((size_t)T_TOK * 4);
  float* pw1   = (float*)alloc((size_t)T_TOK * 4);
  float* pw2   = (float*)alloc((size_t)T_TOK * 4);
  int*   cnt   = (int*)alloc(NE * 4);
  int*   offs  = (int*)alloc(NE * 4);
  int*   tok_c = (int*)alloc((size_t)CAP * 4);
  float* wgt_c = (float*)alloc((size_t)CAP * 4);
  unsigned short* xg   = (unsigned short*)alloc((size_t)CAP * HD * 2);
  unsigned short* hbuf = (unsigned short*)alloc((size_t)CAP * FD * 2);

  hipMemsetAsync(d_out, 0, (size_t)out_size * sizeof(float), stream);
  if (cur > ws_size) return;  // not enough scratch: bail visibly (zeroed out)

  k_gate  <<<T_TOK / 4, 256, 0, stream>>>(x, gw, logits, pe1, pe2, pw1, pw2);
  k_count <<<1, 512, 0, stream>>>(pe1, pe2, cnt, offs);
  k_build <<<NE, 256, 0, stream>>>(pe1, pe2, pw1, pw2, cnt, offs, tok_c, wgt_c);
  k_gather<<<dim3(T_TOK / 8, NE), 256, 0, stream>>>(x, tok_c, cnt, offs, xg);
  k_gemm1 <<<dim3(FD / 64, T_TOK / 128, NE), 256, 0, stream>>>(xg, w1, w3, hbuf, cnt, offs);
  k_gemm2 <<<dim3(HD / 128, T_TOK / 128, NE), 256, 0, stream>>>(hbuf, w2, out, cnt, offs, tok_c, wgt_c);
}

// Round 2
// 1087.538 us; speedup vs baseline: 1.2711x; 1.2711x over previous
//
#include <hip/hip_runtime.h>
#include <hip/hip_bf16.h>
#include <cstdint>

#define T_TOK 8192
#define HD 1024
#define FD 4096
#define NE 8
#define CAP 17408  /* 16384 assignments + 8*128 alignment pad */

typedef __attribute__((ext_vector_type(8))) short bf16x8;
typedef __attribute__((ext_vector_type(4))) float f32x4;

// fp32 -> bf16 round-to-nearest-even (inputs finite)
__device__ __forceinline__ unsigned short f2bf(float f) {
  union { float f; unsigned int u; } a; a.f = f;
  unsigned int r = a.u + 0x7fffu + ((a.u >> 16) & 1u);
  return (unsigned short)(r >> 16);
}

// XOR swizzle within a 128B LDS row: spreads 16B column-slices across banks
#define SWZ(row, kb) ((kb) ^ (((row) & 7) << 4))

// async global->LDS, 16B per lane; LDS dest is wave-uniform base + lane*16
__device__ __forceinline__ void async16(unsigned short* lds, const void* g) {
  __builtin_amdgcn_global_load_lds(
      (const __attribute__((address_space(1))) void*)g,
      (__attribute__((address_space(3))) void*)lds, 16, 0, 0);
}

// ---------------------------------------------------------------- weight cvt fp32->bf16
__global__ __launch_bounds__(256) void k_cvt(const float* __restrict__ src,
                                             unsigned short* __restrict__ dst, int n8) {
  int i = blockIdx.x * blockDim.x + threadIdx.x;
  int stride = gridDim.x * blockDim.x;
  for (; i < n8; i += stride) {
    const float4* s = (const float4*)src + (size_t)i * 2;
    float4 a = s[0], b = s[1];
    union { unsigned short us[8]; int4 v; } p;
    p.us[0] = f2bf(a.x); p.us[1] = f2bf(a.y); p.us[2] = f2bf(a.z); p.us[3] = f2bf(a.w);
    p.us[4] = f2bf(b.x); p.us[5] = f2bf(b.y); p.us[6] = f2bf(b.z); p.us[7] = f2bf(b.w);
    ((int4*)dst)[i] = p.v;
  }
}

// ---------------------------------------------------------------- gating
__global__ __launch_bounds__(256) void k_gate(
    const float* __restrict__ x, const float* __restrict__ gw,
    float* __restrict__ logits, int* __restrict__ pe1, int* __restrict__ pe2,
    float* __restrict__ pw1, float* __restrict__ pw2) {
  int wid = threadIdx.x >> 6, lane = threadIdx.x & 63;
  int t = blockIdx.x * 4 + wid;
  const float* xr = x + (size_t)t * HD;
  float acc[NE];
#pragma unroll
  for (int e = 0; e < NE; ++e) acc[e] = 0.f;
  for (int j = 0; j < HD / 64; ++j) {
    float xv = xr[j * 64 + lane];
#pragma unroll
    for (int e = 0; e < NE; ++e) acc[e] += xv * gw[e * HD + j * 64 + lane];
  }
#pragma unroll
  for (int e = 0; e < NE; ++e) {
    float v = acc[e];
#pragma unroll
    for (int m = 32; m; m >>= 1) v += __shfl_xor(v, m, 64);
    acc[e] = v;
  }
  if (lane < NE) {
    float v = acc[0];
#pragma unroll
    for (int e = 1; e < NE; ++e) if (lane == e) v = acc[e];
    logits[(size_t)t * NE + lane] = v;
  }
  int i1 = 0; float m1 = acc[0];
#pragma unroll
  for (int e = 1; e < NE; ++e) if (acc[e] > m1) { m1 = acc[e]; i1 = e; }
  int i2 = -1; float m2 = -3.4e38f;
#pragma unroll
  for (int e = 0; e < NE; ++e) if (e != i1 && acc[e] > m2) { m2 = acc[e]; i2 = e; }
  float z  = expf(m2 - m1);
  float wa = 1.f / (1.f + z);
  float wb = z  / (1.f + z);
  if (lane == 0) { pe1[t] = i1; pe2[t] = i2; pw1[t] = wa; pw2[t] = wb; }
}

// ---------------------------------------------------------------- counts + 128-aligned offsets
__global__ void k_count(const int* __restrict__ pe1, const int* __restrict__ pe2,
                        int* __restrict__ cnt, int* __restrict__ off) {
  __shared__ int sc[NE];
  int wid = threadIdx.x >> 6, lane = threadIdx.x & 63;
  int c = 0;
  for (int t = lane; t < T_TOK; t += 64) c += (pe1[t] == wid) + (pe2[t] == wid);
#pragma unroll
  for (int m = 32; m; m >>= 1) c += __shfl_xor(c, m, 64);
  if (lane == 0) sc[wid] = c;
  __syncthreads();
  if (threadIdx.x == 0) {
    int o = 0;
    for (int e = 0; e < NE; ++e) { cnt[e] = sc[e]; off[e] = o; o += (sc[e] + 127) & ~127; }
  }
}

// ---------------------------------------------------------------- stable per-expert token lists
__global__ void k_build(const int* __restrict__ pe1, const int* __restrict__ pe2,
                        const float* __restrict__ pw1, const float* __restrict__ pw2,
                        const int* __restrict__ cnt, const int* __restrict__ off,
                        int* __restrict__ tok_c, float* __restrict__ wgt_c) {
  int e = blockIdx.x;
  int base = off[e], n = cnt[e];
  __shared__ int sc[256];
  int written = 0;
  for (int c0 = 0; c0 < T_TOK; c0 += 1024) {
    int tb = c0 + threadIdx.x * 4;
    int f[4]; float w[4]; int fc = 0;
#pragma unroll
    for (int q = 0; q < 4; ++q) {
      int t = tb + q;
      int a = (pe1[t] == e), b = (pe2[t] == e);
      f[q] = a | b;
      w[q] = a ? pw1[t] : pw2[t];
      fc += f[q];
    }
    sc[threadIdx.x] = fc;
    __syncthreads();
    for (int s = 1; s < 256; s <<= 1) {
      int v = sc[threadIdx.x];
      int u = (threadIdx.x >= s) ? sc[threadIdx.x - s] : 0;
      __syncthreads();
      sc[threadIdx.x] = v + u;
      __syncthreads();
    }
    int excl = sc[threadIdx.x] - fc;
    int tot  = sc[255];
    int pos  = base + written + excl;
#pragma unroll
    for (int q = 0; q < 4; ++q)
      if (f[q]) { tok_c[pos] = tb + q; wgt_c[pos] = w[q]; ++pos; }
    written += tot;
    __syncthreads();
  }
  int aligned = (n + 127) & ~127;
  for (int i = n + threadIdx.x; i < aligned; i += 256) { tok_c[base + i] = 0; wgt_c[base + i] = 0.f; }
}

// ---------------------------------------------------------------- gather x rows -> bf16, expert-sorted
__global__ __launch_bounds__(256) void k_gather(
    const float* __restrict__ x, const int* __restrict__ tok_c,
    const int* __restrict__ cnt, const int* __restrict__ off,
    unsigned short* __restrict__ xg) {
  int e = blockIdx.y;
  int n = cnt[e];
  int row = blockIdx.x * 8 + (threadIdx.x >> 5);
  if (row >= n) return;
  int base = off[e];
  int tok = tok_c[base + row];
  int c = threadIdx.x & 31;
  const float4* src = (const float4*)(x + (size_t)tok * HD);
  unsigned short* dst = xg + (size_t)(base + row) * HD;
#pragma unroll
  for (int q = 0; q < 8; ++q) {
    float4 v = src[q * 32 + c];
    ushort4 o;
    o.x = f2bf(v.x); o.y = f2bf(v.y); o.z = f2bf(v.z); o.w = f2bf(v.w);
    *(ushort4*)(dst + (size_t)(q * 32 + c) * 4) = o;
  }
}

// ---------------------------------------------------------------- GEMM1: g=x@w1^T, u=x@w3^T, h=silu(g)*u
// BM=128, BN=64 (per matrix), BK=64, 4 waves (2x2), 16x16x32 bf16 MFMA
// sB rows 0-63 = w1 tile, rows 64-127 = w3 tile
template <bool PRECVT>
__global__ __launch_bounds__(256) void k_gemm1(
    const unsigned short* __restrict__ xg,
    const float* __restrict__ w1f, const float* __restrict__ w3f,
    const unsigned short* __restrict__ w1b, const unsigned short* __restrict__ w3b,
    unsigned short* __restrict__ h,
    const int* __restrict__ cnt, const int* __restrict__ off) {
  int e = blockIdx.z;
  int n_e = cnt[e];
  int mt0 = blockIdx.y * 128;
  if (mt0 >= n_e) return;
  int base = off[e];
  int n0 = blockIdx.x * 64;
  __shared__ unsigned short sA[128 * 64];
  __shared__ unsigned short sB[128 * 64];
  int tid = threadIdx.x;
  int wid = tid >> 6, lane = tid & 63;
  int wr = wid >> 1, wc = wid & 1;
  f32x4 accg[4][2], accu[4][2];
#pragma unroll
  for (int i = 0; i < 4; ++i)
#pragma unroll
    for (int j = 0; j < 2; ++j) {
      accg[i][j] = f32x4{0.f, 0.f, 0.f, 0.f};
      accu[i][j] = f32x4{0.f, 0.f, 0.f, 0.f};
    }

  const char* Ab = (const char*)(xg + (size_t)(base + mt0) * HD);
  // bf16 path pointers
  const char* B1c = (const char*)(w1b + (size_t)e * FD * HD + (size_t)n0 * HD);
  const char* B3c = (const char*)(w3b + (size_t)e * FD * HD + (size_t)n0 * HD);
  const char* Bsel = (wid < 2) ? B1c : B3c;
  // fp32 fallback pointers
  const float* B1g = w1f + (size_t)e * FD * HD + (size_t)n0 * HD;
  const float* B3g = w3f + (size_t)e * FD * HD + (size_t)n0 * HD;
  int brow = tid >> 2, bcol = (tid & 3) * 16;  // fallback: 16 f32/thread/matrix

  for (int k0 = 0; k0 < HD; k0 += 64) {
    __syncthreads();
    // ---- stage A (bf16, global_load_lds, pre-swizzled source) ----
#pragma unroll
    for (int q = 0; q < 4; ++q) {
      int row = wid * 32 + q * 8 + (lane >> 3);
      int scb = ((lane & 7) * 16) ^ ((row & 7) << 4);
      async16(sA + wid * 2048 + q * 512, Ab + (size_t)row * (HD * 2) + k0 * 2 + scb);
    }
    if constexpr (PRECVT) {
      // ---- stage B1+B3 (bf16, global_load_lds) ----
#pragma unroll
      for (int q = 0; q < 4; ++q) {
        int r = wid * 32 + q * 8 + (lane >> 3);  // 0..127 (sB row)
        int rr = r & 63;                          // row within w1/w3 tile
        int scb = ((lane & 7) * 16) ^ ((r & 7) << 4);
        async16(sB + wid * 2048 + q * 512, Bsel + (size_t)rr * (HD * 2) + k0 * 2 + scb);
      }
    } else {
      // ---- stage B1/B3 with fp32->bf16 cvt (fallback) ----
      const float4* s1 = (const float4*)(B1g + (size_t)brow * HD + k0 + bcol);
      const float4* s3 = (const float4*)(B3g + (size_t)brow * HD + k0 + bcol);
      char* d1 = (char*)sB + brow * 128;
      char* d3 = (char*)sB + 64 * 128 + brow * 128;
      union { unsigned short us[8]; int4 v; } p;
#pragma unroll
      for (int hh = 0; hh < 2; ++hh) {
        float4 a = s1[hh * 2 + 0], b = s1[hh * 2 + 1];
        p.us[0] = f2bf(a.x); p.us[1] = f2bf(a.y); p.us[2] = f2bf(a.z); p.us[3] = f2bf(a.w);
        p.us[4] = f2bf(b.x); p.us[5] = f2bf(b.y); p.us[6] = f2bf(b.z); p.us[7] = f2bf(b.w);
        *(int4*)(d1 + SWZ(brow, bcol * 2 + hh * 16)) = p.v;
      }
#pragma unroll
      for (int hh = 0; hh < 2; ++hh) {
        float4 a = s3[hh * 2 + 0], b = s3[hh * 2 + 1];
        p.us[0] = f2bf(a.x); p.us[1] = f2bf(a.y); p.us[2] = f2bf(a.z); p.us[3] = f2bf(a.w);
        p.us[4] = f2bf(b.x); p.us[5] = f2bf(b.y); p.us[6] = f2bf(b.z); p.us[7] = f2bf(b.w);
        *(int4*)(d3 + SWZ(brow, bcol * 2 + hh * 16)) = p.v;
      }
    }
    __syncthreads();
#pragma unroll
    for (int kk = 0; kk < 2; ++kk) {
      int kb = kk * 64 + (lane >> 4) * 16;
      bf16x8 af[4], b1f[2], b2f[2];
#pragma unroll
      for (int mt = 0; mt < 4; ++mt) {
        int r = wr * 64 + mt * 16 + (lane & 15);
        af[mt] = *(const bf16x8*)((const char*)sA + r * 128 + SWZ(r, kb));
      }
#pragma unroll
      for (int nt = 0; nt < 2; ++nt) {
        int r = wc * 32 + nt * 16 + (lane & 15);
        b1f[nt] = *(const bf16x8*)((const char*)sB + r * 128 + SWZ(r, kb));
        b2f[nt] = *(const bf16x8*)((const char*)sB + (64 + r) * 128 + SWZ(r, kb));
      }
#pragma unroll
      for (int mt = 0; mt < 4; ++mt)
#pragma unroll
        for (int nt = 0; nt < 2; ++nt) {
          accg[mt][nt] = __builtin_amdgcn_mfma_f32_16x16x32_bf16(af[mt], b1f[nt], accg[mt][nt], 0, 0, 0);
          accu[mt][nt] = __builtin_amdgcn_mfma_f32_16x16x32_bf16(af[mt], b2f[nt], accu[mt][nt], 0, 0, 0);
        }
    }
  }
  // epilogue: h = silu(g)*u -> bf16 (C/D: col=lane&15, row=(lane>>4)*4+r)
#pragma unroll
  for (int mt = 0; mt < 4; ++mt) {
    int rbase = wr * 64 + mt * 16 + ((lane >> 4) << 2);
#pragma unroll
    for (int r = 0; r < 4; ++r) {
      int lrow = rbase + r;
      if (mt0 + lrow < n_e) {
        size_t hrow = (size_t)(base + mt0 + lrow) * FD;
#pragma unroll
        for (int nt = 0; nt < 2; ++nt) {
          int col = n0 + wc * 32 + nt * 16 + (lane & 15);
          float g = accg[mt][nt][r], u = accu[mt][nt][r];
          float s = g / (1.f + expf(-g));
          h[hrow + col] = f2bf(s * u);
        }
      }
    }
  }
}

// ---------------------------------------------------------------- GEMM2: y=h@w2^T, out[tok]+=w*y
// BM=128, BN=128, BK=64, 4 waves (2x2)
template <bool PRECVT>
__global__ __launch_bounds__(256) void k_gemm2(
    const unsigned short* __restrict__ h,
    const float* __restrict__ w2f, const unsigned short* __restrict__ w2b,
    float* __restrict__ out,
    const int* __restrict__ cnt, const int* __restrict__ off,
    const int* __restrict__ tok_c, const float* __restrict__ wgt_c) {
  int e = blockIdx.z;
  int n_e = cnt[e];
  int mt0 = blockIdx.y * 128;
  if (mt0 >= n_e) return;
  int base = off[e];
  int n0 = blockIdx.x * 128;
  __shared__ unsigned short sA[128 * 64];
  __shared__ unsigned short sB[128 * 64];
  int tid = threadIdx.x, wid = tid >> 6, lane = tid & 63;
  int wr = wid >> 1, wc = wid & 1;
  f32x4 acc[4][4];
#pragma unroll
  for (int i = 0; i < 4; ++i)
#pragma unroll
    for (int j = 0; j < 4; ++j) acc[i][j] = f32x4{0.f, 0.f, 0.f, 0.f};

  const char* Ab = (const char*)(h + (size_t)(base + mt0) * FD);
  const char* Bc = (const char*)(w2b + (size_t)e * HD * FD + (size_t)n0 * FD);
  const float* Bg = w2f + (size_t)e * HD * FD + (size_t)n0 * FD;
  int brow = tid >> 1, bcol = (tid & 1) * 32;  // fallback: 32 f32/thread

  for (int k0 = 0; k0 < FD; k0 += 64) {
    __syncthreads();
    // ---- stage A (h, bf16, global_load_lds) ----
#pragma unroll
    for (int q = 0; q < 4; ++q) {
      int row = wid * 32 + q * 8 + (lane >> 3);
      int scb = ((lane & 7) * 16) ^ ((row & 7) << 4);
      async16(sA + wid * 2048 + q * 512, Ab + (size_t)row * (FD * 2) + k0 * 2 + scb);
    }
    if constexpr (PRECVT) {
#pragma unroll
      for (int q = 0; q < 4; ++q) {
        int r = wid * 32 + q * 8 + (lane >> 3);
        int scb = ((lane & 7) * 16) ^ ((r & 7) << 4);
        async16(sB + wid * 2048 + q * 512, Bc + (size_t)r * (FD * 2) + k0 * 2 + scb);
      }
    } else {
      const float4* src = (const float4*)(Bg + (size_t)brow * FD + k0 + bcol);
      char* drow = (char*)sB + brow * 128;
      union { unsigned short us[8]; int4 v; } p;
#pragma unroll
      for (int q = 0; q < 4; ++q) {
        float4 a = src[q * 2 + 0], b = src[q * 2 + 1];
        p.us[0] = f2bf(a.x); p.us[1] = f2bf(a.y); p.us[2] = f2bf(a.z); p.us[3] = f2bf(a.w);
        p.us[4] = f2bf(b.x); p.us[5] = f2bf(b.y); p.us[6] = f2bf(b.z); p.us[7] = f2bf(b.w);
        *(int4*)(drow + SWZ(brow, bcol * 2 + q * 16)) = p.v;
      }
    }
    __syncthreads();
#pragma unroll
    for (int kk = 0; kk < 2; ++kk) {
      int kb = kk * 64 + (lane >> 4) * 16;
      bf16x8 af[4], bfv[4];
#pragma unroll
      for (int mt = 0; mt < 4; ++mt) {
        int r = wr * 64 + mt * 16 + (lane & 15);
        af[mt] = *(const bf16x8*)((const char*)sA + r * 128 + SWZ(r, kb));
      }
#pragma unroll
      for (int nt = 0; nt < 4; ++nt) {
        int r = wc * 64 + nt * 16 + (lane & 15);
        bfv[nt] = *(const bf16x8*)((const char*)sB + r * 128 + SWZ(r, kb));
      }
#pragma unroll
      for (int mt = 0; mt < 4; ++mt)
#pragma unroll
        for (int nt = 0; nt < 4; ++nt)
          acc[mt][nt] = __builtin_amdgcn_mfma_f32_16x16x32_bf16(af[mt], bfv[nt], acc[mt][nt], 0, 0, 0);
    }
  }
  // epilogue: weighted scatter-add (each token has exactly 2 experts)
#pragma unroll
  for (int mt = 0; mt < 4; ++mt) {
    int rbase = wr * 64 + mt * 16 + ((lane >> 4) << 2);
#pragma unroll
    for (int r = 0; r < 4; ++r) {
      int grow = mt0 + rbase + r;
      if (grow < n_e) {
        int tok = tok_c[base + grow];
        float wgt = wgt_c[base + grow];
        float* orow = out + (size_t)tok * HD;
#pragma unroll
        for (int nt = 0; nt < 4; ++nt) {
          int col = n0 + wc * 64 + nt * 16 + (lane & 15);
          atomicAdd(orow + col, wgt * acc[mt][nt][r]);
        }
      }
    }
  }
}

// ----------------------------------------------------------------
extern "C" void kernel_launch(void* const* d_in, const int* in_sizes, int n_in,
                              void* d_out, int out_size, void* d_ws, size_t ws_size,
                              hipStream_t stream) {
  const float* x  = (const float*)d_in[0];
  const float* gw = (const float*)d_in[1];
  const float* w1 = (const float*)d_in[2];
  const float* w2 = (const float*)d_in[3];
  const float* w3 = (const float*)d_in[4];
  float* out = (float*)d_out;
  float* logits = out + (size_t)T_TOK * HD;

  char* wsp = (char*)d_ws;
  size_t cur = 0;
  auto alloc = [&](size_t bytes) {
    char* p = wsp + cur;
    cur += (bytes + 255) & ~(size_t)255;
    return p;
  };
  int*   pe1   = (int*)alloc((size_t)T_TOK * 4);
  int*   pe2   = (int*)alloc((size_t)T_TOK * 4);
  float* pw1   = (float*)alloc((size_t)T_TOK * 4);
  float* pw2   = (float*)alloc((size_t)T_TOK * 4);
  int*   cnt   = (int*)alloc(NE * 4);
  int*   offs  = (int*)alloc(NE * 4);
  int*   tok_c = (int*)alloc((size_t)CAP * 4);
  float* wgt_c = (float*)alloc((size_t)CAP * 4);
  unsigned short* xg   = (unsigned short*)alloc((size_t)CAP * HD * 2);
  unsigned short* hbuf = (unsigned short*)alloc((size_t)CAP * FD * 2);
  size_t base_need = cur;

  const size_t WELEM = (size_t)NE * FD * HD;  // elements per w1/w2/w3
  unsigned short* w1b = (unsigned short*)alloc(WELEM * 2);
  unsigned short* w3b = (unsigned short*)alloc(WELEM * 2);
  unsigned short* w2b = (unsigned short*)alloc(WELEM * 2);
  bool precvt = (cur <= ws_size);  // host-side constant across calls

  hipMemsetAsync(d_out, 0, (size_t)out_size * sizeof(float), stream);
  if (base_need > ws_size) return;  // cannot run at all (zeroed out, visible fail)

  k_gate  <<<T_TOK / 4, 256, 0, stream>>>(x, gw, logits, pe1, pe2, pw1, pw2);
  k_count <<<1, 512, 0, stream>>>(pe1, pe2, cnt, offs);
  k_build <<<NE, 256, 0, stream>>>(pe1, pe2, pw1, pw2, cnt, offs, tok_c, wgt_c);
  k_gather<<<dim3(T_TOK / 8, NE), 256, 0, stream>>>(x, tok_c, cnt, offs, xg);

  if (precvt) {
    int n8 = (int)(WELEM / 8);
    k_cvt<<<2048, 256, 0, stream>>>(w1, w1b, n8);
    k_cvt<<<2048, 256, 0, stream>>>(w3, w3b, n8);
    k_cvt<<<2048, 256, 0, stream>>>(w2, w2b, n8);
    k_gemm1<true><<<dim3(FD / 64, T_TOK / 128, NE), 256, 0, stream>>>(
        xg, w1, w3, w1b, w3b, hbuf, cnt, offs);
    k_gemm2<true><<<dim3(HD / 128, T_TOK / 128, NE), 256, 0, stream>>>(
        hbuf, w2, w2b, out, cnt, offs, tok_c, wgt_c);
  } else {
    k_gemm1<false><<<dim3(FD / 64, T_TOK / 128, NE), 256, 0, stream>>>(
        xg, w1, w3, w1b, w3b, hbuf, cnt, offs);
    k_gemm2<false><<<dim3(HD / 128, T_TOK / 128, NE), 256, 0, stream>>>(
        hbuf, w2, w2b, out, cnt, offs, tok_c, wgt_c);
  }
}